// Round 3
// baseline (97.323 us; speedup 1.0000x reference)
//
#include <hip/hip_runtime.h>
#include <math.h>

#define H 2048
#define DIN 1024
#define DOUT 1024
#define NL 4

__device__ __forceinline__ float wave_reduce_sum(float v) {
    #pragma unroll
    for (int off = 32; off; off >>= 1) v += __shfl_down(v, off);
    return v;
}

// Split-K GEMV: one output row per block. Thread t owns K-chunk elements
// [c*BLOCK*4 + t*4, +4) — contiguous float4 per instruction, fully coalesced.
template <int BLOCK, int K>
__global__ __launch_bounds__(BLOCK) void gemv_splitk(const float* __restrict__ W,
                                                     const float* __restrict__ x,
                                                     const float* __restrict__ b,
                                                     float* __restrict__ y) {
    const int row = blockIdx.x;
    const int tid = threadIdx.x;
    const float* rp = W + (size_t)row * K;
    float acc = 0.f;
    constexpr int CH = K / (BLOCK * 4);
    #pragma unroll
    for (int c = 0; c < CH; ++c) {
        int idx = c * BLOCK * 4 + tid * 4;
        float4 w  = *reinterpret_cast<const float4*>(rp + idx);
        float4 xv = *reinterpret_cast<const float4*>(x + idx);
        acc = fmaf(w.x, xv.x, acc); acc = fmaf(w.y, xv.y, acc);
        acc = fmaf(w.z, xv.z, acc); acc = fmaf(w.w, xv.w, acc);
    }
    acc = wave_reduce_sum(acc);
    __shared__ float part[BLOCK / 64];
    const int wid = tid >> 6, lane = tid & 63;
    if (lane == 0) part[wid] = acc;
    __syncthreads();
    if (tid == 0) {
        float s = part[0];
        #pragma unroll
        for (int i = 1; i < BLOCK / 64; ++i) s += part[i];
        y[row] = s + b[row];
    }
}

// Fused split-K GRU layer step: one output element per 512-thread block.
// 6 dots ({r,z,n} x {W_ih over carry, W_hh over h0[l]}) + gate math.
// Thread t owns elements [t*4, t*4+4) of K=H=2048 (512*4 = 2048, one chunk).
__global__ __launch_bounds__(512) void gru_layer_splitk(
    const float* __restrict__ Wi,    // [3H, H] this layer
    const float* __restrict__ Wh,    // [3H, H] this layer
    const float* __restrict__ bi,    // [3H]
    const float* __restrict__ bh,    // [3H]
    const float* __restrict__ hprev, // [H] = h0[l]
    const float* __restrict__ cin,   // [H]
    float* __restrict__ cout,        // [H]
    float* __restrict__ hid_out) {   // [H] slice of d_out
    const int row = blockIdx.x;
    const int tid = threadIdx.x;
    const int idx = tid * 4;
    const float* ir_row = Wi + (size_t)row * H;
    const float* iz_row = Wi + (size_t)(row + H) * H;
    const float* in_row = Wi + (size_t)(row + 2 * H) * H;
    const float* hr_row = Wh + (size_t)row * H;
    const float* hz_row = Wh + (size_t)(row + H) * H;
    const float* hn_row = Wh + (size_t)(row + 2 * H) * H;

    float4 xv = *reinterpret_cast<const float4*>(cin + idx);
    float4 hv = *reinterpret_cast<const float4*>(hprev + idx);
    float4 w0 = *reinterpret_cast<const float4*>(ir_row + idx);
    float4 w1 = *reinterpret_cast<const float4*>(iz_row + idx);
    float4 w2 = *reinterpret_cast<const float4*>(in_row + idx);
    float4 w3 = *reinterpret_cast<const float4*>(hr_row + idx);
    float4 w4 = *reinterpret_cast<const float4*>(hz_row + idx);
    float4 w5 = *reinterpret_cast<const float4*>(hn_row + idx);

    float air = w0.x * xv.x + w0.y * xv.y + w0.z * xv.z + w0.w * xv.w;
    float aiz = w1.x * xv.x + w1.y * xv.y + w1.z * xv.z + w1.w * xv.w;
    float ain = w2.x * xv.x + w2.y * xv.y + w2.z * xv.z + w2.w * xv.w;
    float ahr = w3.x * hv.x + w3.y * hv.y + w3.z * hv.z + w3.w * hv.w;
    float ahz = w4.x * hv.x + w4.y * hv.y + w4.z * hv.z + w4.w * hv.w;
    float ahn = w5.x * hv.x + w5.y * hv.y + w5.z * hv.z + w5.w * hv.w;

    air = wave_reduce_sum(air);
    aiz = wave_reduce_sum(aiz);
    ain = wave_reduce_sum(ain);
    ahr = wave_reduce_sum(ahr);
    ahz = wave_reduce_sum(ahz);
    ahn = wave_reduce_sum(ahn);

    __shared__ float part[8][6];
    const int wid = tid >> 6, lane = tid & 63;
    if (lane == 0) {
        part[wid][0] = air; part[wid][1] = aiz; part[wid][2] = ain;
        part[wid][3] = ahr; part[wid][4] = ahz; part[wid][5] = ahn;
    }
    __syncthreads();
    if (tid == 0) {
        float s[6];
        #pragma unroll
        for (int g = 0; g < 6; ++g) {
            float v = part[0][g];
            #pragma unroll
            for (int w = 1; w < 8; ++w) v += part[w][g];
            s[g] = v;
        }
        float ir  = s[0] + bi[row];
        float iz  = s[1] + bi[H + row];
        float inn = s[2] + bi[2 * H + row];
        float hr  = s[3] + bh[row];
        float hz  = s[4] + bh[H + row];
        float hn  = s[5] + bh[2 * H + row];
        float r = 1.f / (1.f + expf(-(ir + hr)));
        float z = 1.f / (1.f + expf(-(iz + hz)));
        float n = tanhf(inn + r * hn);
        float h = hprev[row];
        float hnew = (1.f - z) * n + z * h;
        cout[row] = hnew;
        hid_out[row] = hnew;
    }
}

extern "C" void kernel_launch(void* const* d_in, const int* in_sizes, int n_in,
                              void* d_out, int out_size, void* d_ws, size_t ws_size,
                              hipStream_t stream) {
    const float* x    = (const float*)d_in[0];
    const float* h0   = (const float*)d_in[1];
    const float* encW = (const float*)d_in[2];
    const float* encb = (const float*)d_in[3];
    const float* Wih  = (const float*)d_in[4];
    const float* Whh  = (const float*)d_in[5];
    const float* bih  = (const float*)d_in[6];
    const float* bhh  = (const float*)d_in[7];
    const float* decW = (const float*)d_in[8];
    const float* decb = (const float*)d_in[9];
    float* out = (float*)d_out;

    float* vec0 = (float*)d_ws;      // [H]
    float* vec1 = vec0 + H;          // [H]

    // 1) encoder: [1,1024] -> [1,2048]; one row per 256-thread block
    gemv_splitk<256, DIN><<<H, 256, 0, stream>>>(encW, x, encb, vec0);
    // 2) sequential fused GRU layers, ping-pong carry; one row per 512-thread block
    const float* cin = vec0;
    float* cout = vec1;
    for (int l = 0; l < NL; ++l) {
        gru_layer_splitk<<<H, 512, 0, stream>>>(
            Wih + (size_t)l * 3 * H * H, Whh + (size_t)l * 3 * H * H,
            bih + l * 3 * H, bhh + l * 3 * H,
            h0 + l * H, cin, cout, out + DOUT + l * H);
        float* t = cout; cout = (float*)cin; cin = t;
    }
    // 3) decoder: [1,2048] -> [1,1024]; one row per 512-thread block
    gemv_splitk<512, H><<<DOUT, 512, 0, stream>>>(decW, cin, decb, out);
}